// Round 7
// baseline (337.209 us; speedup 1.0000x reference)
//
#include <hip/hip_runtime.h>
#include <hip/hip_fp16.h>
#include <math.h>

#define NN   50000
#define EE   1600000
#define FD   128
#define OUTD 40
#define NEG  0.2f
#define NB   196           // ceil(NN/256) buckets of 256 nodes
#define ABLK 256           // pass-A blocks
#define ACH  (EE/ABLK)     // 6250 edges per pass-A block (exact)
#define BCAP 12288         // LDS staging capacity (mean 8163)

__device__ __forceinline__ float lrelu(float v) { return v > 0.f ? v : NEG * v; }

__device__ __forceinline__ int fenc(float f) { int b = __float_as_int(f); return b < 0 ? (b ^ 0x7FFFFFFF) : b; }
__device__ __forceinline__ float fdec(int v) { v = v < 0 ? (v ^ 0x7FFFFFFF) : v; return __int_as_float(v); }

struct alignas(8) half4 { __half2 lo, hi; };

// ---------------- precompute collapsed weights ----------------
__global__ __launch_bounds__(256) void k_precompute(
    const float* __restrict__ Wr0, const float* __restrict__ ar0, const float* __restrict__ br0,
    const float* __restrict__ Wr1, const float* __restrict__ ar1, const float* __restrict__ br1,
    const float* __restrict__ Wm1, const float* __restrict__ bm1,
    const float* __restrict__ Wm2, const float* __restrict__ bm2,
    float* __restrict__ wrv0, float* __restrict__ brd0,
    float* __restrict__ wrv1, float* __restrict__ brd1,
    float* __restrict__ Wp, float* __restrict__ bp, int* __restrict__ mAL)
{
  int gid = blockIdx.x * 256 + threadIdx.x;
  if (gid < 256) {
    int k = gid >> 1, h = gid & 1;
    float s = 0.f;
    for (int c = 0; c < 64; ++c) s += Wr0[k*FD + h*64 + c] * ar0[h*64 + c];
    wrv0[k*2 + h] = s;
  } else if (gid < 512) {
    int idx = gid - 256; int k = idx >> 1, h = idx & 1;
    float s = 0.f;
    for (int c = 0; c < 64; ++c) s += Wr1[k*FD + h*64 + c] * ar1[h*64 + c];
    wrv1[k*2 + h] = s;
  } else if (gid < 512 + FD*OUTD) {
    int idx = gid - 512; int k = idx / OUTD, o = idx % OUTD;
    float s = 0.f;
    for (int j = 0; j < 64; ++j) s += Wm1[k*64 + j] * Wm2[j*OUTD + o];
    Wp[k*OUTD + o] = s;
  } else if (gid < 512 + FD*OUTD + OUTD) {
    int o = gid - (512 + FD*OUTD);
    float s = bm2[o];
    for (int j = 0; j < 64; ++j) s += bm1[j] * Wm2[j*OUTD + o];
    bp[o] = s;
  } else if (gid < 512 + FD*OUTD + OUTD + 4) {
    int idx = gid - (512 + FD*OUTD + OUTD);
    int l = idx >> 1, h = idx & 1;
    const float* br = l ? br1 : br0;
    const float* ar = l ? ar1 : ar0;
    float s = 0.f;
    for (int c = 0; c < 64; ++c) s += br[h*64 + c] * ar[h*64 + c];
    (l ? brd1 : brd0)[h] = s;
  } else if (gid < 512 + FD*OUTD + OUTD + 8) {
    mAL[gid - (512 + FD*OUTD + OUTD + 4)] = 0x80000000;
  }
}

// ---------------- fused GEMM + alpha_l + alpha_r + per-layer AL-max ----------------
__global__ __launch_bounds__(256) void k_gemm_alpha(
    const float* __restrict__ X, const float* __restrict__ Wl, const float* __restrict__ bl,
    const float* __restrict__ al, const float* __restrict__ wrv, const float* __restrict__ brd,
    __half* __restrict__ XLh, float* __restrict__ AL, float* __restrict__ AR,
    int* __restrict__ mAL)
{
  __shared__ float sW[FD*FD];
  __shared__ float sX[32*FD];
  __shared__ int smaxI[2];
  int t = threadIdx.x;
  int base = blockIdx.x * 32;
  if (t < 2) smaxI[t] = 0x80000000;
  {
    const float4* W4 = (const float4*)Wl;
    float4* sW4 = (float4*)sW;
    #pragma unroll
    for (int i = 0; i < 16; ++i) sW4[t + i*256] = W4[t + i*256];
    int rows = NN - base; if (rows > 32) rows = 32;
    int nf4 = rows * 32;
    const float4* X4 = (const float4*)(X + (size_t)base * FD);
    float4* sX4 = (float4*)sX;
    #pragma unroll
    for (int i = 0; i < 4; ++i) {
      int idx = t + i*256;
      sX4[idx] = (idx < nf4) ? X4[idx] : make_float4(0.f,0.f,0.f,0.f);
    }
  }
  __syncthreads();
  int cg = t & 31, rg = t >> 5;
  int c0 = cg * 4;
  float acc[4][4] = {};
  #pragma unroll 4
  for (int k = 0; k < FD; ++k) {
    float4 wv = *(const float4*)&sW[k*FD + c0];
    #pragma unroll
    for (int r = 0; r < 4; ++r) {
      float xv = sX[(rg*4+r)*FD + k];
      acc[r][0] = fmaf(xv, wv.x, acc[r][0]);
      acc[r][1] = fmaf(xv, wv.y, acc[r][1]);
      acc[r][2] = fmaf(xv, wv.z, acc[r][2]);
      acc[r][3] = fmaf(xv, wv.w, acc[r][3]);
    }
  }
  float4 bias = *(const float4*)&bl[c0];
  int lane = t & 63;
  int head = cg >> 4;
  const float* alh = al + head*64 + (c0 & 63);
  float a0_0 = alh[0], a0_1 = alh[1], a0_2 = alh[2], a0_3 = alh[3];
  float mloc = -INFINITY;
  #pragma unroll
  for (int r = 0; r < 4; ++r) {
    int row = base + rg*4 + r;
    float4 o;
    o.x = acc[r][0] + bias.x; o.y = acc[r][1] + bias.y;
    o.z = acc[r][2] + bias.z; o.w = acc[r][3] + bias.w;
    if (row < NN) {
      half4 hv; hv.lo = __floats2half2_rn(o.x, o.y); hv.hi = __floats2half2_rn(o.z, o.w);
      *(half4*)&XLh[(size_t)row*FD + c0] = hv;
    }
    float av = o.x*a0_0 + o.y*a0_1 + o.z*a0_2 + o.w*a0_3;
    #pragma unroll
    for (int off = 1; off < 16; off <<= 1) av += __shfl_xor(av, off);
    if (row < NN) {
      mloc = fmaxf(mloc, av);
      if ((lane & 15) == 0) AL[(size_t)row*2 + head] = av;
    }
    float p0 = 0.f, p1 = 0.f;
    #pragma unroll
    for (int j = 0; j < 4; ++j) {
      float xv = sX[(rg*4+r)*FD + c0 + j];
      p0 = fmaf(xv, wrv[(c0+j)*2 + 0], p0);
      p1 = fmaf(xv, wrv[(c0+j)*2 + 1], p1);
    }
    #pragma unroll
    for (int off = 1; off < 32; off <<= 1) { p0 += __shfl_xor(p0, off); p1 += __shfl_xor(p1, off); }
    if ((lane & 31) == 0 && row < NN) {
      AR[(size_t)row*2 + 0] = p0 + brd[0];
      AR[(size_t)row*2 + 1] = p1 + brd[1];
    }
  }
  // block max of AL per head -> 2 global atomics
  mloc = fmaxf(mloc, __shfl_xor(mloc, 32));
  if (lane < 32 && (lane & 15) == 0) atomicMax(&smaxI[head], fenc(mloc));
  __syncthreads();
  if (t < 2) atomicMax(&mAL[t], smaxI[t]);
}

// ================= bucket CSR build =================
__global__ __launch_bounds__(256) void k_bhist(const int* __restrict__ dst, int* __restrict__ gbcnt) {
  __shared__ int hist[NB];
  int t = threadIdx.x;
  if (t < NB) hist[t] = 0;
  __syncthreads();
  int e0 = blockIdx.x * ACH;
  for (int e = e0 + t; e < e0 + ACH; e += 256)
    atomicAdd(&hist[dst[e] >> 8], 1);
  __syncthreads();
  if (t < NB) atomicAdd(&gbcnt[t], hist[t]);
}

__global__ __launch_bounds__(256) void k_bscan(const int* __restrict__ gbcnt,
                                               int* __restrict__ boff, int* __restrict__ gcur,
                                               int* __restrict__ row_off) {
  __shared__ int tmp[256];
  int t = threadIdx.x;
  int v = (t < NB) ? gbcnt[t] : 0;
  tmp[t] = v;
  __syncthreads();
  #pragma unroll
  for (int off = 1; off < 256; off <<= 1) {
    int u = (t >= off) ? tmp[t - off] : 0;
    __syncthreads();
    tmp[t] += u;
    __syncthreads();
  }
  int excl = tmp[t] - v;
  if (t < NB) { boff[t] = excl; gcur[t] = excl; }
  if (t == 0) { boff[NB] = EE; row_off[NN] = EE; }
}

__global__ __launch_bounds__(256) void k_bplace(const int* __restrict__ src, const int* __restrict__ dst,
    int* __restrict__ gcur, unsigned int* __restrict__ pair_buf) {
  __shared__ int hist[NB];
  __shared__ int base_l[NB];
  __shared__ int lcur[NB];
  int t = threadIdx.x;
  if (t < NB) { hist[t] = 0; lcur[t] = 0; }
  __syncthreads();
  int e0 = blockIdx.x * ACH;
  for (int e = e0 + t; e < e0 + ACH; e += 256)
    atomicAdd(&hist[dst[e] >> 8], 1);
  __syncthreads();
  if (t < NB) base_l[t] = atomicAdd(&gcur[t], hist[t]);
  __syncthreads();
  for (int e = e0 + t; e < e0 + ACH; e += 256) {
    int d = dst[e];
    int b = d >> 8;
    int p = base_l[b] + atomicAdd(&lcur[b], 1);
    pair_buf[p] = (unsigned int)src[e] | ((unsigned int)(d & 255) << 16);
  }
}

__global__ __launch_bounds__(256) void k_bfinal(const unsigned int* __restrict__ pair_buf,
    const int* __restrict__ boff, int* __restrict__ row_off,
    unsigned short* __restrict__ csr16) {
  __shared__ int hist[256];
  __shared__ int rel[256];
  __shared__ unsigned short stage[BCAP];
  int g = blockIdx.x;
  int t = threadIdx.x;
  int e0 = boff[g], e1 = boff[g+1];
  int cnt = e1 - e0;
  hist[t] = 0;
  __syncthreads();
  for (int i = e0 + t; i < e1; i += 256)
    atomicAdd(&hist[pair_buf[i] >> 16], 1);
  __syncthreads();
  int v = hist[t];
  rel[t] = v;
  __syncthreads();
  #pragma unroll
  for (int off = 1; off < 256; off <<= 1) {
    int u = (t >= off) ? rel[t - off] : 0;
    __syncthreads();
    rel[t] += u;
    __syncthreads();
  }
  int excl = rel[t] - v;
  __syncthreads();
  rel[t] = excl;
  int node = g*256 + t;
  if (node < NN) row_off[node] = e0 + excl;
  hist[t] = 0;
  __syncthreads();
  bool staged = (cnt <= BCAP);
  for (int i = e0 + t; i < e1; i += 256) {
    unsigned int p = pair_buf[i];
    int j = p >> 16;
    int l = atomicAdd(&hist[j], 1);
    if (staged) stage[rel[j] + l] = (unsigned short)(p & 0xFFFF);
    else        csr16[e0 + rel[j] + l] = (unsigned short)(p & 0xFFFF);
  }
  __syncthreads();
  if (staged)
    for (int i = t; i < cnt; i += 256) csr16[e0 + i] = stage[i];
}

// ---------------- fused attention + aggregation ----------------
__global__ __launch_bounds__(256) void k_agg(
    const __half* __restrict__ XLh, const float* __restrict__ AL,
    const float* __restrict__ AR, const int* __restrict__ mAL,
    const int* __restrict__ row_off, const unsigned short* __restrict__ csr16,
    float* __restrict__ OUT)
{
  int node = blockIdx.x * 4 + (threadIdx.x >> 6);
  if (node >= NN) return;
  int lane = threadIdx.x & 63;
  int g = lane >> 4, l = lane & 15;
  bool h1 = (l & 8) != 0;
  float2 ar = ((const float2*)AR)[node];
  float m0 = lrelu(fdec(mAL[0]) + ar.x);
  float m1 = lrelu(fdec(mAL[1]) + ar.y);
  float ar_s = h1 ? ar.y : ar.x;
  float m_s  = h1 ? m1 : m0;
  int beg = row_off[node], end = row_off[node+1];
  float acc[8] = {};
  float s_acc = 0.f;
  for (int i = beg; i < end; i += 8) {
    int iA = i + g, iB = i + 4 + g;
    bool vA = iA < end, vB = iB < end;
    int eA = vA ? iA : beg;
    int eB = vB ? iB : beg;
    int sA = csr16[eA];
    int sB = csr16[eB];
    float2 alA = ((const float2*)AL)[sA];
    float2 alB = ((const float2*)AL)[sB];
    uint4 dA = *(const uint4*)(XLh + (size_t)sA*FD + 8*l);
    uint4 dB = *(const uint4*)(XLh + (size_t)sB*FD + 8*l);
    float wA = __expf(lrelu((h1 ? alA.y : alA.x) + ar_s) - m_s);
    float wB = __expf(lrelu((h1 ? alB.y : alB.x) + ar_s) - m_s);
    wA = vA ? wA : 0.f;
    wB = vB ? wB : 0.f;
    s_acc += wA + wB;
    const __half2* hA = (const __half2*)&dA;
    const __half2* hB = (const __half2*)&dB;
    #pragma unroll
    for (int q = 0; q < 4; ++q) {
      float2 fA = __half22float2(hA[q]);
      float2 fB = __half22float2(hB[q]);
      acc[2*q]   = fmaf(wA, fA.x, acc[2*q]);
      acc[2*q+1] = fmaf(wA, fA.y, acc[2*q+1]);
      acc[2*q]   = fmaf(wB, fB.x, acc[2*q]);
      acc[2*q+1] = fmaf(wB, fB.y, acc[2*q+1]);
    }
  }
  #pragma unroll
  for (int off = 16; off < 64; off <<= 1) {
    s_acc += __shfl_xor(s_acc, off);
    #pragma unroll
    for (int q = 0; q < 8; ++q) acc[q] += __shfl_xor(acc[q], off);
  }
  if (g == 0) {
    float sinv = 1.f / (s_acc + 1e-16f);
    float4 o0, o1;
    o0.x = fmaxf(acc[0]*sinv, 0.f); o0.y = fmaxf(acc[1]*sinv, 0.f);
    o0.z = fmaxf(acc[2]*sinv, 0.f); o0.w = fmaxf(acc[3]*sinv, 0.f);
    o1.x = fmaxf(acc[4]*sinv, 0.f); o1.y = fmaxf(acc[5]*sinv, 0.f);
    o1.z = fmaxf(acc[6]*sinv, 0.f); o1.w = fmaxf(acc[7]*sinv, 0.f);
    *(float4*)&OUT[(size_t)node*FD + 8*l]     = o0;
    *(float4*)&OUT[(size_t)node*FD + 8*l + 4] = o1;
  }
}

// ---------------- post_mp (collapsed) + log_softmax, tiled GEMM ----------------
// 64 nodes/block; 4 threads per node x 10 cols each; H-tile + Wp in LDS
__global__ __launch_bounds__(256) void k_post(
    const float* __restrict__ H, const float* __restrict__ Wp, const float* __restrict__ bp,
    float* __restrict__ out)
{
  __shared__ float sW[FD*OUTD];       // 20.5 KB
  __shared__ float sB[OUTD];
  __shared__ float sX[64][FD+1];      // 33 KB, +1 pad kills bank conflicts
  int t = threadIdx.x;
  for (int i = t; i < FD*OUTD; i += 256) sW[i] = Wp[i];
  if (t < OUTD) sB[t] = bp[t];
  int base = blockIdx.x * 64;
  int rows = NN - base; if (rows > 64) rows = 64;
  const float4* H4 = (const float4*)(H + (size_t)base * FD);
  int nf4 = rows * (FD/4);
  for (int i = t; i < nf4; i += 256) {
    float4 v = H4[i];
    int n = i >> 5, c = (i & 31) * 4;
    sX[n][c] = v.x; sX[n][c+1] = v.y; sX[n][c+2] = v.z; sX[n][c+3] = v.w;
  }
  __syncthreads();
  int n = t >> 2, cg = t & 3;
  int node = base + n;
  float acc[10];
  #pragma unroll
  for (int j = 0; j < 10; ++j) acc[j] = sB[cg*10 + j];
  #pragma unroll 4
  for (int k = 0; k < FD; ++k) {
    float xv = sX[n][k];
    const float* wrow = &sW[k*OUTD + cg*10];
    #pragma unroll
    for (int j = 0; j < 10; ++j) acc[j] = fmaf(xv, wrow[j], acc[j]);
  }
  // log_softmax across the 4 threads of this node
  float m = acc[0];
  #pragma unroll
  for (int j = 1; j < 10; ++j) m = fmaxf(m, acc[j]);
  m = fmaxf(m, __shfl_xor(m, 1));
  m = fmaxf(m, __shfl_xor(m, 2));
  float s = 0.f;
  #pragma unroll
  for (int j = 0; j < 10; ++j) s += __expf(acc[j] - m);
  s += __shfl_xor(s, 1);
  s += __shfl_xor(s, 2);
  float lg = m + __logf(s);
  if (node < NN) {
    #pragma unroll
    for (int j = 0; j < 10; ++j) out[(size_t)node*OUTD + cg*10 + j] = acc[j] - lg;
  }
}

// ---------------- launch ----------------
extern "C" void kernel_launch(void* const* d_in, const int* in_sizes, int n_in,
                              void* d_out, int out_size, void* d_ws, size_t ws_size,
                              hipStream_t stream)
{
  const float* x   = (const float*)d_in[0];
  const int*   ei  = (const int*)d_in[1];
  const float* Wl0 = (const float*)d_in[2];
  const float* bl0 = (const float*)d_in[3];
  const float* Wr0 = (const float*)d_in[4];
  const float* br0 = (const float*)d_in[5];
  const float* al0 = (const float*)d_in[6];
  const float* ar0 = (const float*)d_in[7];
  const float* Wl1 = (const float*)d_in[8];
  const float* bl1 = (const float*)d_in[9];
  const float* Wr1 = (const float*)d_in[10];
  const float* br1 = (const float*)d_in[11];
  const float* al1 = (const float*)d_in[12];
  const float* ar1 = (const float*)d_in[13];
  const float* Wm1 = (const float*)d_in[14];
  const float* bm1 = (const float*)d_in[15];
  const float* Wm2 = (const float*)d_in[16];
  const float* bm2 = (const float*)d_in[17];
  const int* srcA = ei;
  const int* dstA = ei + EE;

  char* w = (char*)d_ws;
  __half* XLh    = (__half*)w;  w += (size_t)NN*FD*2;    // 12.8 MB
  float* bufB    = (float*)w;  w += (size_t)NN*FD*4;     // 25.6 MB
  float* AL      = (float*)w;  w += (size_t)NN*2*4;
  float* AR      = (float*)w;  w += (size_t)NN*2*4;
  float* wrv0    = (float*)w;  w += 256*4;
  float* wrv1    = (float*)w;  w += 256*4;
  float* brd0    = (float*)w;  w += 16;
  float* brd1    = (float*)w;  w += 16;
  float* Wp      = (float*)w;  w += FD*OUTD*4;
  float* bp      = (float*)w;  w += 64*4;
  int* mAL       = (int*)w;    w += 4*4;
  int* gbcnt     = (int*)w;    w += NB*4;
  int* gcur      = (int*)w;    w += NB*4;
  int* boff      = (int*)w;    w += (NB+1)*4 + 12;
  int* row_off   = (int*)w;    w += (size_t)(NN+1)*4 + 12;
  unsigned int* pair_buf = (unsigned int*)w; w += (size_t)EE*4;  // 6.4 MB
  unsigned short* csr16  = (unsigned short*)w; w += (size_t)EE*2; // 3.2 MB

  hipMemsetAsync(gbcnt, 0, NB*4, stream);

  k_precompute<<<23, 256, 0, stream>>>(Wr0, ar0, br0, Wr1, ar1, br1, Wm1, bm1, Wm2, bm2,
                                       wrv0, brd0, wrv1, brd1, Wp, bp, mAL);

  // CSR build (shared by both layers): bucket two-phase, LDS-confined randomness
  k_bhist<<<ABLK, 256, 0, stream>>>(dstA, gbcnt);
  k_bscan<<<1, 256, 0, stream>>>(gbcnt, boff, gcur, row_off);
  k_bplace<<<ABLK, 256, 0, stream>>>(srcA, dstA, gcur, pair_buf);
  k_bfinal<<<NB, 256, 0, stream>>>(pair_buf, boff, row_off, csr16);

  // layer 0
  k_gemm_alpha<<<(NN+31)/32, 256, 0, stream>>>(x, Wl0, bl0, al0, wrv0, brd0, XLh, AL, AR, mAL + 0);
  k_agg<<<(NN+3)/4, 256, 0, stream>>>(XLh, AL, AR, mAL + 0, row_off, csr16, bufB);
  // layer 1
  k_gemm_alpha<<<(NN+31)/32, 256, 0, stream>>>(bufB, Wl1, bl1, al1, wrv1, brd1, XLh, AL, AR, mAL + 2);
  k_agg<<<(NN+3)/4, 256, 0, stream>>>(XLh, AL, AR, mAL + 2, row_off, csr16, bufB);
  // post_mp + log_softmax
  k_post<<<(NN+63)/64, 256, 0, stream>>>(bufB, Wp, bp, (float*)d_out);
}

// Round 8
// 292.293 us; speedup vs baseline: 1.1537x; 1.1537x over previous
//
#include <hip/hip_runtime.h>
#include <hip/hip_fp16.h>
#include <math.h>

#define NN   50000
#define EE   1600000
#define FD   128
#define OUTD 40
#define NEG  0.2f
#define NB   196           // ceil(NN/256) buckets of 256 nodes
#define ABLK 256           // pass-A blocks
#define ACH  (EE/ABLK)     // 6250 edges per pass-A block (exact)
#define BCAP 12288         // LDS staging capacity (mean 8163)

__device__ __forceinline__ float lrelu(float v) { return v > 0.f ? v : NEG * v; }

__device__ __forceinline__ int fenc(float f) { int b = __float_as_int(f); return b < 0 ? (b ^ 0x7FFFFFFF) : b; }
__device__ __forceinline__ float fdec(int v) { v = v < 0 ? (v ^ 0x7FFFFFFF) : v; return __int_as_float(v); }

struct alignas(8) half4 { __half2 lo, hi; };

// ---------------- precompute collapsed weights ----------------
__global__ __launch_bounds__(256) void k_precompute(
    const float* __restrict__ Wr0, const float* __restrict__ ar0, const float* __restrict__ br0,
    const float* __restrict__ Wr1, const float* __restrict__ ar1, const float* __restrict__ br1,
    const float* __restrict__ Wm1, const float* __restrict__ bm1,
    const float* __restrict__ Wm2, const float* __restrict__ bm2,
    float* __restrict__ wrv0, float* __restrict__ brd0,
    float* __restrict__ wrv1, float* __restrict__ brd1,
    float* __restrict__ Wp, float* __restrict__ bp, int* __restrict__ mAL)
{
  int gid = blockIdx.x * 256 + threadIdx.x;
  if (gid < 256) {
    int k = gid >> 1, h = gid & 1;
    float s = 0.f;
    for (int c = 0; c < 64; ++c) s += Wr0[k*FD + h*64 + c] * ar0[h*64 + c];
    wrv0[k*2 + h] = s;
  } else if (gid < 512) {
    int idx = gid - 256; int k = idx >> 1, h = idx & 1;
    float s = 0.f;
    for (int c = 0; c < 64; ++c) s += Wr1[k*FD + h*64 + c] * ar1[h*64 + c];
    wrv1[k*2 + h] = s;
  } else if (gid < 512 + FD*OUTD) {
    int idx = gid - 512; int k = idx / OUTD, o = idx % OUTD;
    float s = 0.f;
    for (int j = 0; j < 64; ++j) s += Wm1[k*64 + j] * Wm2[j*OUTD + o];
    Wp[k*OUTD + o] = s;
  } else if (gid < 512 + FD*OUTD + OUTD) {
    int o = gid - (512 + FD*OUTD);
    float s = bm2[o];
    for (int j = 0; j < 64; ++j) s += bm1[j] * Wm2[j*OUTD + o];
    bp[o] = s;
  } else if (gid < 512 + FD*OUTD + OUTD + 4) {
    int idx = gid - (512 + FD*OUTD + OUTD);
    int l = idx >> 1, h = idx & 1;
    const float* br = l ? br1 : br0;
    const float* ar = l ? ar1 : ar0;
    float s = 0.f;
    for (int c = 0; c < 64; ++c) s += br[h*64 + c] * ar[h*64 + c];
    (l ? brd1 : brd0)[h] = s;
  } else if (gid < 512 + FD*OUTD + OUTD + 8) {
    mAL[gid - (512 + FD*OUTD + OUTD + 4)] = 0x80000000;
  }
}

// ---------------- fused GEMM + alpha_l + alpha_r + per-layer AL-max ----------------
// X-tile (32 rows) in LDS only; W read per-k through L1/L2 (64KB, shared by all
// blocks). LDS 16.5KB -> ~3 blocks/CU (VGPR-bound) instead of 1 (was 82KB).
__global__ __launch_bounds__(256) void k_gemm_alpha(
    const float* __restrict__ X, const float* __restrict__ Wl, const float* __restrict__ bl,
    const float* __restrict__ al, const float* __restrict__ wrv, const float* __restrict__ brd,
    __half* __restrict__ XLh, float* __restrict__ AL, float* __restrict__ AR,
    int* __restrict__ mAL)
{
  __shared__ float sX[32*FD];
  __shared__ int smaxI[2];
  int t = threadIdx.x;
  int base = blockIdx.x * 32;
  if (t < 2) smaxI[t] = 0x80000000;
  {
    int rows = NN - base; if (rows > 32) rows = 32;
    int nf4 = rows * 32;
    const float4* X4 = (const float4*)(X + (size_t)base * FD);
    float4* sX4 = (float4*)sX;
    #pragma unroll
    for (int i = 0; i < 4; ++i) {
      int idx = t + i*256;
      sX4[idx] = (idx < nf4) ? X4[idx] : make_float4(0.f,0.f,0.f,0.f);
    }
  }
  __syncthreads();
  int cg = t & 31, rg = t >> 5;
  int c0 = cg * 4;
  float acc[4][4] = {};
  #pragma unroll 8
  for (int k = 0; k < FD; ++k) {
    float4 wv = *(const float4*)&Wl[k*FD + c0];
    #pragma unroll
    for (int r = 0; r < 4; ++r) {
      float xv = sX[(rg*4+r)*FD + k];
      acc[r][0] = fmaf(xv, wv.x, acc[r][0]);
      acc[r][1] = fmaf(xv, wv.y, acc[r][1]);
      acc[r][2] = fmaf(xv, wv.z, acc[r][2]);
      acc[r][3] = fmaf(xv, wv.w, acc[r][3]);
    }
  }
  float4 bias = *(const float4*)&bl[c0];
  int lane = t & 63;
  int head = cg >> 4;
  const float* alh = al + head*64 + (c0 & 63);
  float a0_0 = alh[0], a0_1 = alh[1], a0_2 = alh[2], a0_3 = alh[3];
  float mloc = -INFINITY;
  #pragma unroll
  for (int r = 0; r < 4; ++r) {
    int row = base + rg*4 + r;
    float4 o;
    o.x = acc[r][0] + bias.x; o.y = acc[r][1] + bias.y;
    o.z = acc[r][2] + bias.z; o.w = acc[r][3] + bias.w;
    if (row < NN) {
      half4 hv; hv.lo = __floats2half2_rn(o.x, o.y); hv.hi = __floats2half2_rn(o.z, o.w);
      *(half4*)&XLh[(size_t)row*FD + c0] = hv;
    }
    float av = o.x*a0_0 + o.y*a0_1 + o.z*a0_2 + o.w*a0_3;
    #pragma unroll
    for (int off = 1; off < 16; off <<= 1) av += __shfl_xor(av, off);
    if (row < NN) {
      mloc = fmaxf(mloc, av);
      if ((lane & 15) == 0) AL[(size_t)row*2 + head] = av;
    }
    float p0 = 0.f, p1 = 0.f;
    #pragma unroll
    for (int j = 0; j < 4; ++j) {
      float xv = sX[(rg*4+r)*FD + c0 + j];
      p0 = fmaf(xv, wrv[(c0+j)*2 + 0], p0);
      p1 = fmaf(xv, wrv[(c0+j)*2 + 1], p1);
    }
    #pragma unroll
    for (int off = 1; off < 32; off <<= 1) { p0 += __shfl_xor(p0, off); p1 += __shfl_xor(p1, off); }
    if ((lane & 31) == 0 && row < NN) {
      AR[(size_t)row*2 + 0] = p0 + brd[0];
      AR[(size_t)row*2 + 1] = p1 + brd[1];
    }
  }
  // block max of AL per head -> 2 global atomics
  mloc = fmaxf(mloc, __shfl_xor(mloc, 32));
  if (lane < 32 && (lane & 15) == 0) atomicMax(&smaxI[head], fenc(mloc));
  __syncthreads();
  if (t < 2) atomicMax(&mAL[t], smaxI[t]);
}

// ================= bucket CSR build =================
__global__ __launch_bounds__(256) void k_bhist(const int* __restrict__ dst, int* __restrict__ gbcnt) {
  __shared__ int hist[NB];
  int t = threadIdx.x;
  if (t < NB) hist[t] = 0;
  __syncthreads();
  int e0 = blockIdx.x * ACH;
  for (int e = e0 + t; e < e0 + ACH; e += 256)
    atomicAdd(&hist[dst[e] >> 8], 1);
  __syncthreads();
  if (t < NB) atomicAdd(&gbcnt[t], hist[t]);
}

__global__ __launch_bounds__(256) void k_bscan(const int* __restrict__ gbcnt,
                                               int* __restrict__ boff, int* __restrict__ gcur,
                                               int* __restrict__ row_off) {
  __shared__ int tmp[256];
  int t = threadIdx.x;
  int v = (t < NB) ? gbcnt[t] : 0;
  tmp[t] = v;
  __syncthreads();
  #pragma unroll
  for (int off = 1; off < 256; off <<= 1) {
    int u = (t >= off) ? tmp[t - off] : 0;
    __syncthreads();
    tmp[t] += u;
    __syncthreads();
  }
  int excl = tmp[t] - v;
  if (t < NB) { boff[t] = excl; gcur[t] = excl; }
  if (t == 0) { boff[NB] = EE; row_off[NN] = EE; }
}

__global__ __launch_bounds__(256) void k_bplace(const int* __restrict__ src, const int* __restrict__ dst,
    int* __restrict__ gcur, unsigned int* __restrict__ pair_buf) {
  __shared__ int hist[NB];
  __shared__ int base_l[NB];
  __shared__ int lcur[NB];
  int t = threadIdx.x;
  if (t < NB) { hist[t] = 0; lcur[t] = 0; }
  __syncthreads();
  int e0 = blockIdx.x * ACH;
  for (int e = e0 + t; e < e0 + ACH; e += 256)
    atomicAdd(&hist[dst[e] >> 8], 1);
  __syncthreads();
  if (t < NB) base_l[t] = atomicAdd(&gcur[t], hist[t]);
  __syncthreads();
  for (int e = e0 + t; e < e0 + ACH; e += 256) {
    int d = dst[e];
    int b = d >> 8;
    int p = base_l[b] + atomicAdd(&lcur[b], 1);
    pair_buf[p] = (unsigned int)src[e] | ((unsigned int)(d & 255) << 16);
  }
}

__global__ __launch_bounds__(256) void k_bfinal(const unsigned int* __restrict__ pair_buf,
    const int* __restrict__ boff, int* __restrict__ row_off,
    unsigned short* __restrict__ csr16) {
  __shared__ int hist[256];
  __shared__ int rel[256];
  __shared__ unsigned short stage[BCAP];
  int g = blockIdx.x;
  int t = threadIdx.x;
  int e0 = boff[g], e1 = boff[g+1];
  int cnt = e1 - e0;
  hist[t] = 0;
  __syncthreads();
  for (int i = e0 + t; i < e1; i += 256)
    atomicAdd(&hist[pair_buf[i] >> 16], 1);
  __syncthreads();
  int v = hist[t];
  rel[t] = v;
  __syncthreads();
  #pragma unroll
  for (int off = 1; off < 256; off <<= 1) {
    int u = (t >= off) ? rel[t - off] : 0;
    __syncthreads();
    rel[t] += u;
    __syncthreads();
  }
  int excl = rel[t] - v;
  __syncthreads();
  rel[t] = excl;
  int node = g*256 + t;
  if (node < NN) row_off[node] = e0 + excl;
  hist[t] = 0;
  __syncthreads();
  bool staged = (cnt <= BCAP);
  for (int i = e0 + t; i < e1; i += 256) {
    unsigned int p = pair_buf[i];
    int j = p >> 16;
    int l = atomicAdd(&hist[j], 1);
    if (staged) stage[rel[j] + l] = (unsigned short)(p & 0xFFFF);
    else        csr16[e0 + rel[j] + l] = (unsigned short)(p & 0xFFFF);
  }
  __syncthreads();
  if (staged)
    for (int i = t; i < cnt; i += 256) csr16[e0 + i] = stage[i];
}

// ---------------- fused attention + aggregation ----------------
__global__ __launch_bounds__(256) void k_agg(
    const __half* __restrict__ XLh, const float* __restrict__ AL,
    const float* __restrict__ AR, const int* __restrict__ mAL,
    const int* __restrict__ row_off, const unsigned short* __restrict__ csr16,
    float* __restrict__ OUT)
{
  int node = blockIdx.x * 4 + (threadIdx.x >> 6);
  if (node >= NN) return;
  int lane = threadIdx.x & 63;
  int g = lane >> 4, l = lane & 15;
  bool h1 = (l & 8) != 0;
  float2 ar = ((const float2*)AR)[node];
  float m0 = lrelu(fdec(mAL[0]) + ar.x);
  float m1 = lrelu(fdec(mAL[1]) + ar.y);
  float ar_s = h1 ? ar.y : ar.x;
  float m_s  = h1 ? m1 : m0;
  int beg = row_off[node], end = row_off[node+1];
  float acc[8] = {};
  float s_acc = 0.f;
  for (int i = beg; i < end; i += 8) {
    int iA = i + g, iB = i + 4 + g;
    bool vA = iA < end, vB = iB < end;
    int eA = vA ? iA : beg;
    int eB = vB ? iB : beg;
    int sA = csr16[eA];
    int sB = csr16[eB];
    float2 alA = ((const float2*)AL)[sA];
    float2 alB = ((const float2*)AL)[sB];
    uint4 dA = *(const uint4*)(XLh + (size_t)sA*FD + 8*l);
    uint4 dB = *(const uint4*)(XLh + (size_t)sB*FD + 8*l);
    float wA = __expf(lrelu((h1 ? alA.y : alA.x) + ar_s) - m_s);
    float wB = __expf(lrelu((h1 ? alB.y : alB.x) + ar_s) - m_s);
    wA = vA ? wA : 0.f;
    wB = vB ? wB : 0.f;
    s_acc += wA + wB;
    const __half2* hA = (const __half2*)&dA;
    const __half2* hB = (const __half2*)&dB;
    #pragma unroll
    for (int q = 0; q < 4; ++q) {
      float2 fA = __half22float2(hA[q]);
      float2 fB = __half22float2(hB[q]);
      acc[2*q]   = fmaf(wA, fA.x, acc[2*q]);
      acc[2*q+1] = fmaf(wA, fA.y, acc[2*q+1]);
      acc[2*q]   = fmaf(wB, fB.x, acc[2*q]);
      acc[2*q+1] = fmaf(wB, fB.y, acc[2*q+1]);
    }
  }
  #pragma unroll
  for (int off = 16; off < 64; off <<= 1) {
    s_acc += __shfl_xor(s_acc, off);
    #pragma unroll
    for (int q = 0; q < 8; ++q) acc[q] += __shfl_xor(acc[q], off);
  }
  if (g == 0) {
    float sinv = 1.f / (s_acc + 1e-16f);
    float4 o0, o1;
    o0.x = fmaxf(acc[0]*sinv, 0.f); o0.y = fmaxf(acc[1]*sinv, 0.f);
    o0.z = fmaxf(acc[2]*sinv, 0.f); o0.w = fmaxf(acc[3]*sinv, 0.f);
    o1.x = fmaxf(acc[4]*sinv, 0.f); o1.y = fmaxf(acc[5]*sinv, 0.f);
    o1.z = fmaxf(acc[6]*sinv, 0.f); o1.w = fmaxf(acc[7]*sinv, 0.f);
    *(float4*)&OUT[(size_t)node*FD + 8*l]     = o0;
    *(float4*)&OUT[(size_t)node*FD + 8*l + 4] = o1;
  }
}

// ---------------- post_mp (collapsed) + log_softmax, tiled GEMM ----------------
__global__ __launch_bounds__(256) void k_post(
    const float* __restrict__ H, const float* __restrict__ Wp, const float* __restrict__ bp,
    float* __restrict__ out)
{
  __shared__ float sW[FD*OUTD];
  __shared__ float sB[OUTD];
  __shared__ float sX[64][FD+1];
  int t = threadIdx.x;
  for (int i = t; i < FD*OUTD; i += 256) sW[i] = Wp[i];
  if (t < OUTD) sB[t] = bp[t];
  int base = blockIdx.x * 64;
  int rows = NN - base; if (rows > 64) rows = 64;
  const float4* H4 = (const float4*)(H + (size_t)base * FD);
  int nf4 = rows * (FD/4);
  for (int i = t; i < nf4; i += 256) {
    float4 v = H4[i];
    int n = i >> 5, c = (i & 31) * 4;
    sX[n][c] = v.x; sX[n][c+1] = v.y; sX[n][c+2] = v.z; sX[n][c+3] = v.w;
  }
  __syncthreads();
  int n = t >> 2, cg = t & 3;
  int node = base + n;
  float acc[10];
  #pragma unroll
  for (int j = 0; j < 10; ++j) acc[j] = sB[cg*10 + j];
  #pragma unroll 4
  for (int k = 0; k < FD; ++k) {
    float xv = sX[n][k];
    const float* wrow = &sW[k*OUTD + cg*10];
    #pragma unroll
    for (int j = 0; j < 10; ++j) acc[j] = fmaf(xv, wrow[j], acc[j]);
  }
  float m = acc[0];
  #pragma unroll
  for (int j = 1; j < 10; ++j) m = fmaxf(m, acc[j]);
  m = fmaxf(m, __shfl_xor(m, 1));
  m = fmaxf(m, __shfl_xor(m, 2));
  float s = 0.f;
  #pragma unroll
  for (int j = 0; j < 10; ++j) s += __expf(acc[j] - m);
  s += __shfl_xor(s, 1);
  s += __shfl_xor(s, 2);
  float lg = m + __logf(s);
  if (node < NN) {
    #pragma unroll
    for (int j = 0; j < 10; ++j) out[(size_t)node*OUTD + cg*10 + j] = acc[j] - lg;
  }
}

// ---------------- launch ----------------
extern "C" void kernel_launch(void* const* d_in, const int* in_sizes, int n_in,
                              void* d_out, int out_size, void* d_ws, size_t ws_size,
                              hipStream_t stream)
{
  const float* x   = (const float*)d_in[0];
  const int*   ei  = (const int*)d_in[1];
  const float* Wl0 = (const float*)d_in[2];
  const float* bl0 = (const float*)d_in[3];
  const float* Wr0 = (const float*)d_in[4];
  const float* br0 = (const float*)d_in[5];
  const float* al0 = (const float*)d_in[6];
  const float* ar0 = (const float*)d_in[7];
  const float* Wl1 = (const float*)d_in[8];
  const float* bl1 = (const float*)d_in[9];
  const float* Wr1 = (const float*)d_in[10];
  const float* br1 = (const float*)d_in[11];
  const float* al1 = (const float*)d_in[12];
  const float* ar1 = (const float*)d_in[13];
  const float* Wm1 = (const float*)d_in[14];
  const float* bm1 = (const float*)d_in[15];
  const float* Wm2 = (const float*)d_in[16];
  const float* bm2 = (const float*)d_in[17];
  const int* srcA = ei;
  const int* dstA = ei + EE;

  char* w = (char*)d_ws;
  __half* XLh    = (__half*)w;  w += (size_t)NN*FD*2;    // 12.8 MB
  float* bufB    = (float*)w;  w += (size_t)NN*FD*4;     // 25.6 MB
  float* AL      = (float*)w;  w += (size_t)NN*2*4;
  float* AR      = (float*)w;  w += (size_t)NN*2*4;
  float* wrv0    = (float*)w;  w += 256*4;
  float* wrv1    = (float*)w;  w += 256*4;
  float* brd0    = (float*)w;  w += 16;
  float* brd1    = (float*)w;  w += 16;
  float* Wp      = (float*)w;  w += FD*OUTD*4;
  float* bp      = (float*)w;  w += 64*4;
  int* mAL       = (int*)w;    w += 4*4;
  int* gbcnt     = (int*)w;    w += NB*4;
  int* gcur      = (int*)w;    w += NB*4;
  int* boff      = (int*)w;    w += (NB+1)*4 + 12;
  int* row_off   = (int*)w;    w += (size_t)(NN+1)*4 + 12;
  unsigned int* pair_buf = (unsigned int*)w; w += (size_t)EE*4;  // 6.4 MB
  unsigned short* csr16  = (unsigned short*)w; w += (size_t)EE*2; // 3.2 MB

  hipMemsetAsync(gbcnt, 0, NB*4, stream);

  k_precompute<<<23, 256, 0, stream>>>(Wr0, ar0, br0, Wr1, ar1, br1, Wm1, bm1, Wm2, bm2,
                                       wrv0, brd0, wrv1, brd1, Wp, bp, mAL);

  // CSR build (shared by both layers): bucket two-phase, LDS-confined randomness
  k_bhist<<<ABLK, 256, 0, stream>>>(dstA, gbcnt);
  k_bscan<<<1, 256, 0, stream>>>(gbcnt, boff, gcur, row_off);
  k_bplace<<<ABLK, 256, 0, stream>>>(srcA, dstA, gcur, pair_buf);
  k_bfinal<<<NB, 256, 0, stream>>>(pair_buf, boff, row_off, csr16);

  // layer 0
  k_gemm_alpha<<<(NN+31)/32, 256, 0, stream>>>(x, Wl0, bl0, al0, wrv0, brd0, XLh, AL, AR, mAL + 0);
  k_agg<<<(NN+3)/4, 256, 0, stream>>>(XLh, AL, AR, mAL + 0, row_off, csr16, bufB);
  // layer 1
  k_gemm_alpha<<<(NN+31)/32, 256, 0, stream>>>(bufB, Wl1, bl1, al1, wrv1, brd1, XLh, AL, AR, mAL + 2);
  k_agg<<<(NN+3)/4, 256, 0, stream>>>(XLh, AL, AR, mAL + 2, row_off, csr16, bufB);
  // post_mp + log_softmax
  k_post<<<(NN+63)/64, 256, 0, stream>>>(bufB, Wp, bp, (float*)d_out);
}

// Round 9
// 242.598 us; speedup vs baseline: 1.3900x; 1.2048x over previous
//
#include <hip/hip_runtime.h>
#include <hip/hip_fp16.h>
#include <math.h>

#define NN   50000
#define EE   1600000
#define FD   128
#define OUTD 40
#define NEG  0.2f
#define NB   196           // ceil(NN/256) buckets of 256 nodes
#define ABLK 256           // pass-A blocks
#define ACH  (EE/ABLK)     // 6250 edges per pass-A block (exact)
#define BCAP 12288         // LDS staging capacity (mean 8192)
#define BPSZ (9*4*64*8)    // packed B elems: 9 col-tiles x 4 k-steps x 64 lanes x 8

__device__ __forceinline__ float lrelu(float v) { return v > 0.f ? v : NEG * v; }

__device__ __forceinline__ int fenc(float f) { int b = __float_as_int(f); return b < 0 ? (b ^ 0x7FFFFFFF) : b; }
__device__ __forceinline__ float fdec(int v) { v = v < 0 ? (v ^ 0x7FFFFFFF) : v; return __int_as_float(v); }

__device__ __forceinline__ unsigned short f2bf(float f) {
  unsigned int u = __float_as_uint(f);
  unsigned int r = u + 0x7FFFu + ((u >> 16) & 1u);
  return (unsigned short)(r >> 16);
}

typedef short bf16x8 __attribute__((ext_vector_type(8)));
typedef float f32x4  __attribute__((ext_vector_type(4)));

// ---------------- precompute collapsed weights ----------------
__global__ __launch_bounds__(256) void k_precompute(
    const float* __restrict__ Wr0, const float* __restrict__ ar0, const float* __restrict__ br0,
    const float* __restrict__ Wr1, const float* __restrict__ ar1, const float* __restrict__ br1,
    const float* __restrict__ Wm1, const float* __restrict__ bm1,
    const float* __restrict__ Wm2, const float* __restrict__ bm2,
    float* __restrict__ wrv0, float* __restrict__ brd0,
    float* __restrict__ wrv1, float* __restrict__ brd1,
    float* __restrict__ Wp, float* __restrict__ bp, int* __restrict__ mAL)
{
  int gid = blockIdx.x * 256 + threadIdx.x;
  if (gid < 256) {
    int k = gid >> 1, h = gid & 1;
    float s = 0.f;
    for (int c = 0; c < 64; ++c) s += Wr0[k*FD + h*64 + c] * ar0[h*64 + c];
    wrv0[k*2 + h] = s;
  } else if (gid < 512) {
    int idx = gid - 256; int k = idx >> 1, h = idx & 1;
    float s = 0.f;
    for (int c = 0; c < 64; ++c) s += Wr1[k*FD + h*64 + c] * ar1[h*64 + c];
    wrv1[k*2 + h] = s;
  } else if (gid < 512 + FD*OUTD) {
    int idx = gid - 512; int k = idx / OUTD, o = idx % OUTD;
    float s = 0.f;
    for (int j = 0; j < 64; ++j) s += Wm1[k*64 + j] * Wm2[j*OUTD + o];
    Wp[k*OUTD + o] = s;
  } else if (gid < 512 + FD*OUTD + OUTD) {
    int o = gid - (512 + FD*OUTD);
    float s = bm2[o];
    for (int j = 0; j < 64; ++j) s += bm1[j] * Wm2[j*OUTD + o];
    bp[o] = s;
  } else if (gid < 512 + FD*OUTD + OUTD + 4) {
    int idx = gid - (512 + FD*OUTD + OUTD);
    int l = idx >> 1, h = idx & 1;
    const float* br = l ? br1 : br0;
    const float* ar = l ? ar1 : ar0;
    float s = 0.f;
    for (int c = 0; c < 64; ++c) s += br[h*64 + c] * ar[h*64 + c];
    (l ? brd1 : brd0)[h] = s;
  } else if (gid < 512 + FD*OUTD + OUTD + 8) {
    mAL[gid - (512 + FD*OUTD + OUTD + 4)] = 0x80000000;
  }
}

// ---------------- pack B = [Wl | wrv] into MFMA-frag layout (bf16) ----------------
// frag convention (must match A-side load): value slot (lane, j) <-> k = 8*(lane>>4)+j,
// col = ct*16 + (lane&15). Consistency between A and B packing is all that matters:
// any hardware k-permutation applies to both and cancels in the K-sum.
__global__ __launch_bounds__(256) void k_pack(const float* __restrict__ Wl,
    const float* __restrict__ wrv, unsigned short* __restrict__ Bp)
{
  int i = blockIdx.x*256 + threadIdx.x;
  if (i >= BPSZ) return;
  int j = i & 7, lane = (i >> 3) & 63, ks = (i >> 9) & 3, ct = i >> 11;
  int k = ks*32 + 8*(lane >> 4) + j;
  int c = lane & 15;
  float v;
  if (ct < 8) v = Wl[k*FD + ct*16 + c];
  else        v = (c < 2) ? wrv[k*2 + c] : 0.f;
  Bp[i] = f2bf(v);
}

// ---------------- convert x (f32) -> bf16 row-major ----------------
__global__ __launch_bounds__(256) void k_convx(const float* __restrict__ X,
                                               unsigned short* __restrict__ XB)
{
  const int n4 = NN*FD/4;
  for (int i = blockIdx.x*256 + threadIdx.x; i < n4; i += gridDim.x*256) {
    float4 v = ((const float4*)X)[i];
    ushort4 o;
    o.x = f2bf(v.x); o.y = f2bf(v.y); o.z = f2bf(v.z); o.w = f2bf(v.w);
    ((ushort4*)XB)[i] = o;
  }
}

// ---------------- MFMA GEMM + alpha_l + alpha_r + AL-max ----------------
// 64 rows/block (4 waves x 16), N=128 (+wrv tile), K=128. B staged in LDS (36KB).
__global__ __launch_bounds__(256) void k_gemm_mfma(
    const unsigned short* __restrict__ XB, const unsigned short* __restrict__ Bp,
    const float* __restrict__ bl, const float* __restrict__ al, const float* __restrict__ brd,
    __half* __restrict__ XLh, float* __restrict__ AL, float* __restrict__ AR,
    int* __restrict__ mAL)
{
  __shared__ unsigned short sB[BPSZ];   // 36,864 B
  __shared__ int smaxI[2];
  int t = threadIdx.x;
  if (t < 2) smaxI[t] = 0x80000000;
  {
    const uint4* s = (const uint4*)Bp;
    uint4* d = (uint4*)sB;
    #pragma unroll
    for (int i = 0; i < 9; ++i) d[t + i*256] = s[t + i*256];
  }
  __syncthreads();
  int w = t >> 6, l = t & 63;
  int c = l & 15, kg = l >> 4;
  int rowbase = blockIdx.x*64 + w*16;
  int arow = rowbase + c; if (arow > NN-1) arow = NN-1;  // clamped loads; stores guarded
  f32x4 acc[9] = {};
  const bf16x8* sBf = (const bf16x8*)sB;
  #pragma unroll
  for (int ks = 0; ks < 4; ++ks) {
    bf16x8 afrag = *(const bf16x8*)(XB + (size_t)arow*FD + ks*32 + kg*8);
    #pragma unroll
    for (int ct = 0; ct < 9; ++ct)
      acc[ct] = __builtin_amdgcn_mfma_f32_16x16x32_bf16(afrag, sBf[(ct*4+ks)*64 + l], acc[ct], 0, 0, 0);
  }
  // epilogue: D layout col=lane&15, row=4*(lane>>4)+reg  [verified mapping]
  float pAL0[4] = {}, pAL1[4] = {};
  #pragma unroll
  for (int ct = 0; ct < 8; ++ct) {
    float bias = bl[ct*16 + c];
    float alv  = al[ct*16 + c];   // works for both heads: 64+(ct-4)*16 == ct*16
    #pragma unroll
    for (int r = 0; r < 4; ++r) {
      int row = rowbase + kg*4 + r;
      float xv = acc[ct][r] + bias;
      if (row < NN) XLh[(size_t)row*FD + ct*16 + c] = __float2half(xv);
      if (ct < 4) pAL0[r] = fmaf(xv, alv, pAL0[r]);
      else        pAL1[r] = fmaf(xv, alv, pAL1[r]);
    }
  }
  if (c < 2) {
    float b = brd[c];
    #pragma unroll
    for (int r = 0; r < 4; ++r) {
      int row = rowbase + kg*4 + r;
      if (row < NN) AR[(size_t)row*2 + c] = acc[8][r] + b;
    }
  }
  float m0 = -INFINITY, m1 = -INFINITY;
  #pragma unroll
  for (int r = 0; r < 4; ++r) {
    float v0 = pAL0[r], v1 = pAL1[r];
    #pragma unroll
    for (int off = 1; off < 16; off <<= 1) { v0 += __shfl_xor(v0, off); v1 += __shfl_xor(v1, off); }
    int row = rowbase + kg*4 + r;
    if (c == 0 && row < NN) {
      AL[(size_t)row*2 + 0] = v0;
      AL[(size_t)row*2 + 1] = v1;
      m0 = fmaxf(m0, v0); m1 = fmaxf(m1, v1);
    }
  }
  if (c == 0) { atomicMax(&smaxI[0], fenc(m0)); atomicMax(&smaxI[1], fenc(m1)); }
  __syncthreads();
  if (t < 2) atomicMax(&mAL[t], smaxI[t]);
}

// ================= bucket CSR build =================
__global__ __launch_bounds__(256) void k_bhist(const int* __restrict__ dst,
    int* __restrict__ gbcnt, int* __restrict__ blockhist)
{
  __shared__ int hist[NB];
  int t = threadIdx.x;
  if (t < NB) hist[t] = 0;
  __syncthreads();
  int e0 = blockIdx.x * ACH;
  for (int e = e0 + t; e < e0 + ACH; e += 256)
    atomicAdd(&hist[dst[e] >> 8], 1);
  __syncthreads();
  if (t < NB) {
    atomicAdd(&gbcnt[t], hist[t]);
    blockhist[blockIdx.x*NB + t] = hist[t];
  }
}

__global__ __launch_bounds__(256) void k_bscan(const int* __restrict__ gbcnt,
                                               int* __restrict__ boff, int* __restrict__ gcur,
                                               int* __restrict__ row_off) {
  __shared__ int tmp[256];
  int t = threadIdx.x;
  int v = (t < NB) ? gbcnt[t] : 0;
  tmp[t] = v;
  __syncthreads();
  #pragma unroll
  for (int off = 1; off < 256; off <<= 1) {
    int u = (t >= off) ? tmp[t - off] : 0;
    __syncthreads();
    tmp[t] += u;
    __syncthreads();
  }
  int excl = tmp[t] - v;
  if (t < NB) { boff[t] = excl; gcur[t] = excl; }
  if (t == 0) { boff[NB] = EE; row_off[NN] = EE; }
}

__global__ __launch_bounds__(256) void k_bplace(const int* __restrict__ src, const int* __restrict__ dst,
    const int* __restrict__ blockhist, int* __restrict__ gcur, unsigned int* __restrict__ pair_buf)
{
  __shared__ int base_l[NB];
  __shared__ int lcur[NB];
  int t = threadIdx.x;
  if (t < NB) {
    lcur[t] = 0;
    base_l[t] = atomicAdd(&gcur[t], blockhist[blockIdx.x*NB + t]);
  }
  __syncthreads();
  int e0 = blockIdx.x * ACH;
  for (int e = e0 + t; e < e0 + ACH; e += 256) {
    int d = dst[e];
    int b = d >> 8;
    int p = base_l[b] + atomicAdd(&lcur[b], 1);
    pair_buf[p] = (unsigned int)src[e] | ((unsigned int)(d & 255) << 16);
  }
}

__global__ __launch_bounds__(256) void k_bfinal(const unsigned int* __restrict__ pair_buf,
    const int* __restrict__ boff, int* __restrict__ row_off,
    unsigned short* __restrict__ csr16) {
  __shared__ int hist[256];
  __shared__ int rel[256];
  __shared__ unsigned short stage[BCAP];
  int g = blockIdx.x;
  int t = threadIdx.x;
  int e0 = boff[g], e1 = boff[g+1];
  int cnt = e1 - e0;
  hist[t] = 0;
  __syncthreads();
  for (int i = e0 + t; i < e1; i += 256)
    atomicAdd(&hist[pair_buf[i] >> 16], 1);
  __syncthreads();
  int v = hist[t];
  rel[t] = v;
  __syncthreads();
  #pragma unroll
  for (int off = 1; off < 256; off <<= 1) {
    int u = (t >= off) ? rel[t - off] : 0;
    __syncthreads();
    rel[t] += u;
    __syncthreads();
  }
  int excl = rel[t] - v;
  __syncthreads();
  rel[t] = excl;
  int node = g*256 + t;
  if (node < NN) row_off[node] = e0 + excl;
  hist[t] = 0;
  __syncthreads();
  bool staged = (cnt <= BCAP);
  for (int i = e0 + t; i < e1; i += 256) {
    unsigned int p = pair_buf[i];
    int j = p >> 16;
    int l = atomicAdd(&hist[j], 1);
    if (staged) stage[rel[j] + l] = (unsigned short)(p & 0xFFFF);
    else        csr16[e0 + rel[j] + l] = (unsigned short)(p & 0xFFFF);
  }
  __syncthreads();
  if (staged)
    for (int i = t; i < cnt; i += 256) csr16[e0 + i] = stage[i];
}

// ---------------- fused attention + aggregation (csr prefetch pipeline) ----------------
template<bool BF16OUT>
__global__ __launch_bounds__(256) void k_agg(
    const __half* __restrict__ XLh, const float* __restrict__ AL,
    const float* __restrict__ AR, const int* __restrict__ mAL,
    const int* __restrict__ row_off, const unsigned short* __restrict__ csr16,
    float* __restrict__ OUTf, unsigned short* __restrict__ OUTb)
{
  int node = blockIdx.x * 4 + (threadIdx.x >> 6);
  if (node >= NN) return;
  int lane = threadIdx.x & 63;
  int g = lane >> 4, l = lane & 15;
  bool h1 = (l & 8) != 0;
  float2 ar = ((const float2*)AR)[node];
  float m0 = lrelu(fdec(mAL[0]) + ar.x);
  float m1 = lrelu(fdec(mAL[1]) + ar.y);
  float ar_s = h1 ? ar.y : ar.x;
  float m_s  = h1 ? m1 : m0;
  int beg = row_off[node], end = row_off[node+1];
  float acc[8] = {};
  float s_acc = 0.f;
  if (beg < end) {
    int sA = csr16[min(beg + g, end-1)];
    int sB = csr16[min(beg + 4 + g, end-1)];
    for (int i = beg; i < end; i += 8) {
      int curA = sA, curB = sB;
      bool vA = (i + g) < end, vB = (i + 4 + g) < end;
      int ni = i + 8;
      if (ni < end) {
        sA = csr16[min(ni + g, end-1)];
        sB = csr16[min(ni + 4 + g, end-1)];
      }
      float2 alA = ((const float2*)AL)[curA];
      float2 alB = ((const float2*)AL)[curB];
      uint4 dA = *(const uint4*)(XLh + (size_t)curA*FD + 8*l);
      uint4 dB = *(const uint4*)(XLh + (size_t)curB*FD + 8*l);
      float wA = __expf(lrelu((h1 ? alA.y : alA.x) + ar_s) - m_s);
      float wB = __expf(lrelu((h1 ? alB.y : alB.x) + ar_s) - m_s);
      wA = vA ? wA : 0.f;
      wB = vB ? wB : 0.f;
      s_acc += wA + wB;
      const __half2* hA = (const __half2*)&dA;
      const __half2* hB = (const __half2*)&dB;
      #pragma unroll
      for (int q = 0; q < 4; ++q) {
        float2 fA = __half22float2(hA[q]);
        float2 fB = __half22float2(hB[q]);
        acc[2*q]   = fmaf(wA, fA.x, acc[2*q]);
        acc[2*q+1] = fmaf(wA, fA.y, acc[2*q+1]);
        acc[2*q]   = fmaf(wB, fB.x, acc[2*q]);
        acc[2*q+1] = fmaf(wB, fB.y, acc[2*q+1]);
      }
    }
  }
  #pragma unroll
  for (int off = 16; off < 64; off <<= 1) {
    s_acc += __shfl_xor(s_acc, off);
    #pragma unroll
    for (int q = 0; q < 8; ++q) acc[q] += __shfl_xor(acc[q], off);
  }
  if (g == 0) {
    float sinv = 1.f / (s_acc + 1e-16f);
    float o[8];
    #pragma unroll
    for (int q = 0; q < 8; ++q) o[q] = fmaxf(acc[q]*sinv, 0.f);
    if constexpr (BF16OUT) {
      unsigned short ob[8];
      #pragma unroll
      for (int q = 0; q < 8; ++q) ob[q] = f2bf(o[q]);
      *(uint4*)&OUTb[(size_t)node*FD + 8*l] = *(uint4*)ob;
    } else {
      float4 o0, o1;
      o0.x = o[0]; o0.y = o[1]; o0.z = o[2]; o0.w = o[3];
      o1.x = o[4]; o1.y = o[5]; o1.z = o[6]; o1.w = o[7];
      *(float4*)&OUTf[(size_t)node*FD + 8*l]     = o0;
      *(float4*)&OUTf[(size_t)node*FD + 8*l + 4] = o1;
    }
  }
}

// ---------------- post_mp (collapsed) + log_softmax, tiled GEMM ----------------
__global__ __launch_bounds__(256) void k_post(
    const float* __restrict__ H, const float* __restrict__ Wp, const float* __restrict__ bp,
    float* __restrict__ out)
{
  __shared__ float sW[FD*OUTD];
  __shared__ float sB[OUTD];
  __shared__ float sX[64][FD+1];
  int t = threadIdx.x;
  for (int i = t; i < FD*OUTD; i += 256) sW[i] = Wp[i];
  if (t < OUTD) sB[t] = bp[t];
  int base = blockIdx.x * 64;
  int rows = NN - base; if (rows > 64) rows = 64;
  const float4* H4 = (const float4*)(H + (size_t)base * FD);
  int nf4 = rows * (FD/4);
  for (int i = t; i < nf4; i += 256) {
    float4 v = H4[i];
    int n = i >> 5, c = (i & 31) * 4;
    sX[n][c] = v.x; sX[n][c+1] = v.y; sX[n][c+2] = v.z; sX[n][c+3] = v.w;
  }
  __syncthreads();
  int n = t >> 2, cg = t & 3;
  int node = base + n;
  float acc[10];
  #pragma unroll
  for (int j = 0; j < 10; ++j) acc[j] = sB[cg*10 + j];
  #pragma unroll 4
  for (int k = 0; k < FD; ++k) {
    float xv = sX[n][k];
    const float* wrow = &sW[k*OUTD + cg*10];
    #pragma unroll
    for (int j = 0; j < 10; ++j) acc[j] = fmaf(xv, wrow[j], acc[j]);
  }
  float m = acc[0];
  #pragma unroll
  for (int j = 1; j < 10; ++j) m = fmaxf(m, acc[j]);
  m = fmaxf(m, __shfl_xor(m, 1));
  m = fmaxf(m, __shfl_xor(m, 2));
  float s = 0.f;
  #pragma unroll
  for (int j = 0; j < 10; ++j) s += __expf(acc[j] - m);
  s += __shfl_xor(s, 1);
  s += __shfl_xor(s, 2);
  float lg = m + __logf(s);
  if (node < NN) {
    #pragma unroll
    for (int j = 0; j < 10; ++j) out[(size_t)node*OUTD + cg*10 + j] = acc[j] - lg;
  }
}

// ---------------- launch ----------------
extern "C" void kernel_launch(void* const* d_in, const int* in_sizes, int n_in,
                              void* d_out, int out_size, void* d_ws, size_t ws_size,
                              hipStream_t stream)
{
  const float* x   = (const float*)d_in[0];
  const int*   ei  = (const int*)d_in[1];
  const float* Wl0 = (const float*)d_in[2];
  const float* bl0 = (const float*)d_in[3];
  const float* Wr0 = (const float*)d_in[4];
  const float* br0 = (const float*)d_in[5];
  const float* al0 = (const float*)d_in[6];
  const float* ar0 = (const float*)d_in[7];
  const float* Wl1 = (const float*)d_in[8];
  const float* bl1 = (const float*)d_in[9];
  const float* Wr1 = (const float*)d_in[10];
  const float* br1 = (const float*)d_in[11];
  const float* al1 = (const float*)d_in[12];
  const float* ar1 = (const float*)d_in[13];
  const float* Wm1 = (const float*)d_in[14];
  const float* bm1 = (const float*)d_in[15];
  const float* Wm2 = (const float*)d_in[16];
  const float* bm2 = (const float*)d_in[17];
  const int* srcA = ei;
  const int* dstA = ei + EE;

  char* w = (char*)d_ws;
  __half* XLh    = (__half*)w;          w += (size_t)NN*FD*2;   // 12.8 MB
  float* bufB    = (float*)w;           w += (size_t)NN*FD*4;   // 25.6 MB (pair_buf/blockhist overlay)
  unsigned short* XB = (unsigned short*)w; w += (size_t)NN*FD*2; // 12.8 MB (bf16 gemm input)
  float* AL      = (float*)w;  w += (size_t)NN*2*4;
  float* AR      = (float*)w;  w += (size_t)NN*2*4;
  float* wrv0    = (float*)w;  w += 256*4;
  float* wrv1    = (float*)w;  w += 256*4;
  float* brd0    = (float*)w;  w += 16;
  float* brd1    = (float*)w;  w += 16;
  float* Wp      = (float*)w;  w += FD*OUTD*4;
  float* bp      = (float*)w;  w += 64*4;
  int* mAL       = (int*)w;    w += 4*4;
  int* gbcnt     = (int*)w;    w += NB*4;
  int* gcur      = (int*)w;    w += NB*4;
  int* boff      = (int*)w;    w += (NB+1)*4 + 12;
  int* row_off   = (int*)w;    w += (size_t)(NN+1)*4 + 12;
  unsigned short* csr16 = (unsigned short*)w; w += (size_t)EE*2; // 3.2 MB
  unsigned short* Bp0   = (unsigned short*)w; w += BPSZ*2;
  unsigned short* Bp1   = (unsigned short*)w; w += BPSZ*2;
  // overlays into bufB (dead until layer-1 agg writes it):
  unsigned int* pair_buf = (unsigned int*)bufB;                      // 6.4 MB
  int* blockhist = (int*)((char*)bufB + 8*1024*1024);                // 200 KB

  hipMemsetAsync(gbcnt, 0, NB*4, stream);

  k_precompute<<<23, 256, 0, stream>>>(Wr0, ar0, br0, Wr1, ar1, br1, Wm1, bm1, Wm2, bm2,
                                       wrv0, brd0, wrv1, brd1, Wp, bp, mAL);
  k_pack<<<(BPSZ+255)/256, 256, 0, stream>>>(Wl0, wrv0, Bp0);
  k_pack<<<(BPSZ+255)/256, 256, 0, stream>>>(Wl1, wrv1, Bp1);
  k_convx<<<1024, 256, 0, stream>>>(x, XB);

  // CSR build (shared by both layers)
  k_bhist<<<ABLK, 256, 0, stream>>>(dstA, gbcnt, blockhist);
  k_bscan<<<1, 256, 0, stream>>>(gbcnt, boff, gcur, row_off);
  k_bplace<<<ABLK, 256, 0, stream>>>(srcA, dstA, blockhist, gcur, pair_buf);
  k_bfinal<<<NB, 256, 0, stream>>>(pair_buf, boff, row_off, csr16);

  // layer 0
  k_gemm_mfma<<<(NN+63)/64, 256, 0, stream>>>(XB, Bp0, bl0, al0, brd0, XLh, AL, AR, mAL + 0);
  k_agg<true><<<(NN+3)/4, 256, 0, stream>>>(XLh, AL, AR, mAL + 0, row_off, csr16, nullptr, XB);
  // layer 1
  k_gemm_mfma<<<(NN+63)/64, 256, 0, stream>>>(XB, Bp1, bl1, al1, brd1, XLh, AL, AR, mAL + 2);
  k_agg<false><<<(NN+3)/4, 256, 0, stream>>>(XLh, AL, AR, mAL + 2, row_off, csr16, bufB, nullptr);
  // post_mp + log_softmax
  k_post<<<(NN+63)/64, 256, 0, stream>>>(bufB, Wp, bp, (float*)d_out);
}